// Round 8
// baseline (2068.123 us; speedup 1.0000x reference)
//
#include <hip/hip_runtime.h>

// spatialAttentionScaledGCN — MI355X MFMA version.
// B=8, N=512, T=12, F=32, O=64. All I/O fp32.
// R8: ONE fused kernel per Jacobi step (chain 23 -> 12 dispatches; R7 showed
//     ~39 us/dispatch overhead x chain length dominates, work is ~10 us).
//     Per (b,t): 4 blocks x 8 waves (512 thr). Phase A: EACH block computes
//     the full 512-row softmax stats redundantly (wave w: 4 m-tiles, trans-
//     posed score MFMA, 4-stream online softmax) -> MS[512] in 4 KB LDS;
//     one barrier. Phase B: wave w runs R7's pred body for n-tile bx*8+w,
//     MS read from LDS. No atomics, no cross-block sync (R5/R6: fabric sync
//     is ms-scale). launch_bounds(512,4) -> VGPR<=128, 2 blocks/CU, all 352
//     blocks of a dispatch co-resident.

#define B_ 8
#define N_ 512
#define T_ 12
#define F_ 32
#define O_ 64

typedef unsigned int uint_t;
typedef unsigned short ushort_t;
typedef _Float16 f16_t;
typedef _Float16 f16x4 __attribute__((ext_vector_type(4)));
typedef _Float16 f16x8 __attribute__((ext_vector_type(8)));
typedef float f32x4 __attribute__((ext_vector_type(4)));

__device__ __forceinline__ int xidx(int b, int n, int t, int f) {
    return ((b * N_ + n) * T_ + t) * F_ + f;
}
__device__ __forceinline__ f16x8 load_frag8(const float* p) {
    float4 a = *reinterpret_cast<const float4*>(p);
    float4 b = *reinterpret_cast<const float4*>(p + 4);
    f16x8 r;
    r[0] = (f16_t)a.x; r[1] = (f16_t)a.y; r[2] = (f16_t)a.z; r[3] = (f16_t)a.w;
    r[4] = (f16_t)b.x; r[5] = (f16_t)b.y; r[6] = (f16_t)b.z; r[7] = (f16_t)b.w;
    return r;
}
union U2H4 { uint2 u; f16x4 h; };

// ---------------------------------------------------------------------------
// Permute one 512x512 fp32 slice into chunk-pair-interleaved MFMA f16 layout.
// uint4 index per slice: cp*2048 + nt*64 + l; .xy = chunk 2cp rows
// (quad*4 +0..3), .zw = chunk 2cp+1, at column n = nt*16 + (l&15).
__global__ __launch_bounds__(256)
void permute_kernel(const float* __restrict__ src, ushort_t* __restrict__ dst)
{
    __shared__ float Lp[32][516];             // 66 KB
    const int tid = threadIdx.x;
    const int cp  = blockIdx.x;               // 0..15 chunk-pair (32 rows)
    const int s   = blockIdx.y;               // slice (b*12+t for phase; 0 adj)
    src += (size_t)s * N_ * N_ + (size_t)cp * 32 * N_;
    uint4* dstu = (uint4*)dst + (size_t)s * 32768 + (size_t)cp * 2048;

    #pragma unroll
    for (int k = 0; k < 64; ++k) {
        int idx = tid + 256 * k;              // 0..16383
        Lp[idx >> 9][idx & 511] = src[idx];
    }
    __syncthreads();
    #pragma unroll
    for (int k = 0; k < 8; ++k) {
        int u    = tid + 256 * k;             // 0..2047
        int nt   = u >> 6;
        int l    = u & 63;
        int quad = l >> 4;
        int cl   = l & 15;
        int n    = nt * 16 + cl;
        int r0   = quad * 4;
        union { f16_t h[2]; uint_t i; } p0, p1, p2, p3;
        p0.h[0] = (f16_t)Lp[r0][n];      p0.h[1] = (f16_t)Lp[r0 + 1][n];
        p1.h[0] = (f16_t)Lp[r0 + 2][n];  p1.h[1] = (f16_t)Lp[r0 + 3][n];
        p2.h[0] = (f16_t)Lp[16 + r0][n];     p2.h[1] = (f16_t)Lp[16 + r0 + 1][n];
        p3.h[0] = (f16_t)Lp[16 + r0 + 2][n]; p3.h[1] = (f16_t)Lp[16 + r0 + 3][n];
        dstu[u] = make_uint4(p0.i, p1.i, p2.i, p3.i);
    }
}

// ---------------------------------------------------------------------------
// Fused per-step kernel. Grid (4, T', B), 512 thr = 8 waves.
// Phase A: full softmax stats (redundant per block) -> MSl LDS.
// Phase B: pred for n-tile blockIdx.x*8+w.
// FINAL=1: weight *= adj, Xp = X_t (same t), store agg (no mask).
template <int FINAL>
__global__ __launch_bounds__(512, 4)
void fused_kernel(const float* __restrict__ x0,
                  const float* __restrict__ xcur,
                  float* __restrict__ dst,            // xnext or agg
                  const ushort_t* __restrict__ phase_h,
                  const ushort_t* __restrict__ adj_h,
                  const float* __restrict__ mask)
{
    __shared__ float2 MSl[N_];                // 4 KB (M, inv_f/S) per row

    const int tid  = threadIdx.x;
    const int w    = tid >> 6;
    const int l    = tid & 63;
    const int quad = l >> 4;
    const int col  = l & 15;
    const int t    = FINAL ? blockIdx.y : blockIdx.y + 1;
    const int b    = blockIdx.z;
    const float inv_f = 0.17677669529663687f;

    const float* xs     = (FINAL && t == 0) ? x0 : xcur;       // X_t source
    const float* xp_src = FINAL ? xs : ((t == 1) ? x0 : xcur); // pred operand
    const int    tp     = FINAL ? t : t - 1;

    // ================= phase A: stats for m-tiles w*4 .. w*4+3 =============
    for (int mi = 0; mi < 4; ++mi) {
        const int mb = (w * 4 + mi) * 16;
        f16x8 bm = load_frag8(&xs[xidx(b, mb + col, t, quad * 8)]);

        float M[4] = {-1e30f, -1e30f, -1e30f, -1e30f};
        float S[4] = {0.f, 0.f, 0.f, 0.f};
        #pragma unroll 2
        for (int base = 0; base < 8; ++base) {
            #pragma unroll
            for (int ss = 0; ss < 4; ++ss) {
                const int nt2 = base * 4 + ss;
                f16x8 an = load_frag8(&xs[xidx(b, nt2 * 16 + col, t, quad * 8)]);
                f32x4 s4 = __builtin_amdgcn_mfma_f32_16x16x32_f16(
                               an, bm, (f32x4){0.f, 0.f, 0.f, 0.f}, 0, 0, 0);
                float m4 = fmaxf(fmaxf(s4[0], s4[1]), fmaxf(s4[2], s4[3])) * inv_f;
                float Mn = fmaxf(M[ss], m4);
                S[ss] = S[ss] * __expf(M[ss] - Mn)
                      + (__expf(s4[0] * inv_f - Mn) + __expf(s4[1] * inv_f - Mn))
                      + (__expf(s4[2] * inv_f - Mn) + __expf(s4[3] * inv_f - Mn));
                M[ss] = Mn;
            }
        }
        float M01 = fmaxf(M[0], M[1]);
        float S01 = S[0] * __expf(M[0] - M01) + S[1] * __expf(M[1] - M01);
        float M23 = fmaxf(M[2], M[3]);
        float S23 = S[2] * __expf(M[2] - M23) + S[3] * __expf(M[3] - M23);
        float Mm  = fmaxf(M01, M23);
        float Sm  = S01 * __expf(M01 - Mm) + S23 * __expf(M23 - Mm);
        #pragma unroll
        for (int d = 16; d < 64; d <<= 1) {
            float Mo = __shfl_xor(Mm, d, 64), So = __shfl_xor(Sm, d, 64);
            float Mn = fmaxf(Mm, Mo);
            Sm = Sm * __expf(Mm - Mn) + So * __expf(Mo - Mn);
            Mm = Mn;
        }
        if (l < 16)
            MSl[mb + l] = make_float2(Mm, inv_f / Sm);
    }
    __syncthreads();

    // ================= phase B: pred for n-tile bx*8+w =====================
    const int nt = blockIdx.x * 8 + w;
    f16x8 bf = load_frag8(&xs[xidx(b, nt * 16 + col, t, quad * 8)]);
    const uint4* phu4 = (const uint4*)phase_h + (size_t)(b * T_ + t) * 32768
                        + nt * 64 + l;
    const uint4* adu4 = (const uint4*)adj_h + nt * 64 + l;
    const float* msp = (const float*)MSl + quad * 8;     // float2 -> float units

    f32x4 acc0 = (f32x4){0.f, 0.f, 0.f, 0.f};
    f32x4 acc1 = (f32x4){0.f, 0.f, 0.f, 0.f};

    #pragma unroll 2
    for (int cp = 0; cp < 16; ++cp) {
        const int mb0 = cp * 32;
        const int mb1 = mb0 + 16;
        uint4 phq = phu4[cp * 2048];
        uint4 ajq;
        if (FINAL) ajq = adu4[cp * 2048];
        f16x8 af0 = load_frag8(&xs[xidx(b, mb0 + col, t, quad * 8)]);
        f16x8 af1 = load_frag8(&xs[xidx(b, mb1 + col, t, quad * 8)]);
        float4 msA0 = *(const float4*)(msp + mb0 * 2);
        float4 msB0 = *(const float4*)(msp + mb0 * 2 + 4);
        float4 msA1 = *(const float4*)(msp + mb1 * 2);
        float4 msB1 = *(const float4*)(msp + mb1 * 2 + 4);
        f16x4 bp00, bp01, bp10, bp11;
        #pragma unroll
        for (int jj = 0; jj < 4; ++jj) {
            bp00[jj] = (f16_t)xp_src[xidx(b, mb0 + quad * 4 + jj, tp, col)];
            bp01[jj] = (f16_t)xp_src[xidx(b, mb0 + quad * 4 + jj, tp, 16 + col)];
            bp10[jj] = (f16_t)xp_src[xidx(b, mb1 + quad * 4 + jj, tp, col)];
            bp11[jj] = (f16_t)xp_src[xidx(b, mb1 + quad * 4 + jj, tp, 16 + col)];
        }

        f32x4 s40 = __builtin_amdgcn_mfma_f32_16x16x32_f16(
                        af0, bf, (f32x4){0.f, 0.f, 0.f, 0.f}, 0, 0, 0);
        f32x4 s41 = __builtin_amdgcn_mfma_f32_16x16x32_f16(
                        af1, bf, (f32x4){0.f, 0.f, 0.f, 0.f}, 0, 0, 0);

        U2H4 p0; p0.u = make_uint2(phq.x, phq.y);
        U2H4 p1; p1.u = make_uint2(phq.z, phq.w);
        U2H4 a0, a1;
        if (FINAL) { a0.u = make_uint2(ajq.x, ajq.y); a1.u = make_uint2(ajq.z, ajq.w); }

        const float Mv0[4] = {msA0.x, msA0.z, msB0.x, msB0.z};
        const float Sv0[4] = {msA0.y, msA0.w, msB0.y, msB0.w};
        const float Mv1[4] = {msA1.x, msA1.z, msB1.x, msB1.z};
        const float Sv1[4] = {msA1.y, msA1.w, msB1.y, msB1.w};

        f16x4 wf0, wf1;
        #pragma unroll
        for (int v = 0; v < 4; ++v) {
            float e0 = __expf(s40[v] * inv_f - Mv0[v]) * Sv0[v] * (float)p0.h[v];
            float e1 = __expf(s41[v] * inv_f - Mv1[v]) * Sv1[v] * (float)p1.h[v];
            if (FINAL) { e0 *= (float)a0.h[v]; e1 *= (float)a1.h[v]; }
            wf0[v] = (f16_t)e0;
            wf1[v] = (f16_t)e1;
        }
        acc0 = __builtin_amdgcn_mfma_f32_16x16x16f16(wf0, bp00, acc0, 0, 0, 0);
        acc1 = __builtin_amdgcn_mfma_f32_16x16x16f16(wf0, bp01, acc1, 0, 0, 0);
        acc0 = __builtin_amdgcn_mfma_f32_16x16x16f16(wf1, bp10, acc0, 0, 0, 0);
        acc1 = __builtin_amdgcn_mfma_f32_16x16x16f16(wf1, bp11, acc1, 0, 0, 0);
    }

    // ---- epilogue: exactly-once plain stores ----
    #pragma unroll
    for (int v = 0; v < 4; ++v) {
        const int n = nt * 16 + quad * 4 + v;
        if (FINAL) {
            float* d0 = &dst[((size_t)(b * T_ + t) * N_ + n) * F_ + col];
            d0[0]  = acc0[v];
            d0[16] = acc1[v];
        } else {
            const int i0 = xidx(b, n, t, col);
            const float mk = mask[n];
            dst[i0]      = (mk != 0.f) ? xcur[i0]      : acc0[v];
            dst[i0 + 16] = (mk != 0.f) ? xcur[i0 + 16] : acc1[v];
        }
    }
}

// out[b,n,t,o] = relu(sum_f agg[b,t,n,f] * theta[f,o])
__global__ __launch_bounds__(256)
void proj_kernel(const float* __restrict__ agg, const float* __restrict__ theta,
                 float* __restrict__ out)
{
    __shared__ float th[F_ * O_];
    int tid = threadIdx.x;
    #pragma unroll
    for (int p = 0; p < 8; ++p) th[tid + 256 * p] = theta[tid + 256 * p];
    __syncthreads();
    int g  = blockIdx.x * 256 + tid;           // ((b*N+n)*T+t)*O+o
    int o  = g & 63;
    int r  = g >> 6;
    int tt = r % T_;
    int r2 = r / T_;
    int n  = r2 & 511;
    int b  = r2 >> 9;
    const float* a = &agg[((b * T_ + tt) * N_ + n) * F_];
    float s = 0.f;
    #pragma unroll
    for (int f = 0; f < F_; ++f) s += a[f] * th[f * O_ + o];
    out[g] = fmaxf(s, 0.f);
}

extern "C" void kernel_launch(void* const* d_in, const int* in_sizes, int n_in,
                              void* d_out, int out_size, void* d_ws, size_t ws_size,
                              hipStream_t stream)
{
    const float* x     = (const float*)d_in[0];
    const float* phase = (const float*)d_in[1];
    const float* adj   = (const float*)d_in[2];
    const float* mask  = (const float*)d_in[3];
    const float* theta = (const float*)d_in[4];
    float* out = (float*)d_out;

    const size_t XE = (size_t)B_ * N_ * T_ * F_;            // 1,572,864 floats
    float*    xA      = (float*)d_ws;                       //  6.3 MB
    float*    xB      = xA + XE;                            //  6.3 MB
    float*    agg     = xB + XE;                            //  6.3 MB
    ushort_t* phase_h = (ushort_t*)(agg + XE);              // 50.3 MB
    ushort_t* adj_h   = phase_h + (size_t)96 * N_ * N_;     // 0.5 MB

    permute_kernel<<<dim3(16, 96), 256, 0, stream>>>(phase, phase_h);
    permute_kernel<<<dim3(16, 1), 256, 0, stream>>>(adj, adj_h);

    const float* cur = x;
    float* bufs[2] = { xA, xB };
    for (int i = 0; i < T_ - 1; ++i) {                 // 11 Jacobi iterations
        float* nxt = bufs[i & 1];
        fused_kernel<0><<<dim3(4, T_ - 1, B_), 512, 0, stream>>>(
            x, cur, nxt, phase_h, adj_h, mask);
        cur = nxt;
    }
    fused_kernel<1><<<dim3(4, T_, B_), 512, 0, stream>>>(
        x, cur, agg, phase_h, adj_h, mask);
    proj_kernel<<<(B_ * N_ * T_ * O_) / 256, 256, 0, stream>>>(agg, theta, out);
}

// Round 9
// 936.950 us; speedup vs baseline: 2.2073x; 2.2073x over previous
//
#include <hip/hip_runtime.h>

// spatialAttentionScaledGCN — MI355X MFMA version.
// B=8, N=512, T=12, F=32, O=64. All I/O fp32.
// R9: R4/R7 dispatch graph (2 permute + 11x(stats,pred) + final + proj).
//     Both hot kernels rewritten as EXPLICIT software pipelines with ring
//     buffers + full unroll (static indices, no scratch):
//       pred: 32 chunks; phase prefetch depth 8 (4 KB in flight per wave ->
//             ~11 MB device-wide, saturates HBM per Little's law); x/bp/MS
//             staged 1 iter ahead. launch_bounds(256,3) (~170 VGPR cap).
//       stats: x-frag prefetch depth 4; 4-stream online softmax.
//     Rationale: R7 per-layer ~39 us vs ~8 us work = MLP deficit (observed
//     0.4-1 TB/s per kernel); hipcc won't pipeline across iterations itself
//     (R8's VGPR=40 collapse shows the failure mode).

#define B_ 8
#define N_ 512
#define T_ 12
#define F_ 32
#define O_ 64

typedef unsigned int uint_t;
typedef unsigned short ushort_t;
typedef _Float16 f16_t;
typedef _Float16 f16x4 __attribute__((ext_vector_type(4)));
typedef _Float16 f16x8 __attribute__((ext_vector_type(8)));
typedef float f32x4 __attribute__((ext_vector_type(4)));

__device__ __forceinline__ int xidx(int b, int n, int t, int f) {
    return ((b * N_ + n) * T_ + t) * F_ + f;
}
__device__ __forceinline__ f16x8 cvt_frag8(float4 a, float4 b) {
    f16x8 r;
    r[0] = (f16_t)a.x; r[1] = (f16_t)a.y; r[2] = (f16_t)a.z; r[3] = (f16_t)a.w;
    r[4] = (f16_t)b.x; r[5] = (f16_t)b.y; r[6] = (f16_t)b.z; r[7] = (f16_t)b.w;
    return r;
}
__device__ __forceinline__ f16x8 load_frag8(const float* p) {
    return cvt_frag8(*reinterpret_cast<const float4*>(p),
                     *reinterpret_cast<const float4*>(p + 4));
}
union U2H4 { uint2 u; f16x4 h; };

// ---------------------------------------------------------------------------
// Permute one 512x512 fp32 slice into chunk-pair-interleaved MFMA f16 layout.
// uint4 index per slice: cp*2048 + nt*64 + l; .xy = chunk 2cp rows
// (quad*4 +0..3), .zw = chunk 2cp+1, at column n = nt*16 + (l&15).
__global__ __launch_bounds__(256)
void permute_kernel(const float* __restrict__ src, ushort_t* __restrict__ dst)
{
    __shared__ float Lp[32][516];             // 66 KB
    const int tid = threadIdx.x;
    const int cp  = blockIdx.x;               // 0..15 chunk-pair (32 rows)
    const int s   = blockIdx.y;               // slice (b*12+t for phase; 0 adj)
    src += (size_t)s * N_ * N_ + (size_t)cp * 32 * N_;
    uint4* dstu = (uint4*)dst + (size_t)s * 32768 + (size_t)cp * 2048;

    #pragma unroll
    for (int k = 0; k < 64; ++k) {
        int idx = tid + 256 * k;              // 0..16383
        Lp[idx >> 9][idx & 511] = src[idx];
    }
    __syncthreads();
    #pragma unroll
    for (int k = 0; k < 8; ++k) {
        int u    = tid + 256 * k;             // 0..2047
        int nt   = u >> 6;
        int l    = u & 63;
        int quad = l >> 4;
        int cl   = l & 15;
        int n    = nt * 16 + cl;
        int r0   = quad * 4;
        union { f16_t h[2]; uint_t i; } p0, p1, p2, p3;
        p0.h[0] = (f16_t)Lp[r0][n];      p0.h[1] = (f16_t)Lp[r0 + 1][n];
        p1.h[0] = (f16_t)Lp[r0 + 2][n];  p1.h[1] = (f16_t)Lp[r0 + 3][n];
        p2.h[0] = (f16_t)Lp[16 + r0][n];     p2.h[1] = (f16_t)Lp[16 + r0 + 1][n];
        p3.h[0] = (f16_t)Lp[16 + r0 + 2][n]; p3.h[1] = (f16_t)Lp[16 + r0 + 3][n];
        dstu[u] = make_uint4(p0.i, p1.i, p2.i, p3.i);
    }
}

// ---------------------------------------------------------------------------
// Softmax row stats. 704 blocks x 256 thr, no LDS. Wave owns m-tile bx*4+w;
// transposed score MFMA; x-frag prefetch depth 4; 4-stream online softmax.
template <int FINAL>
__global__ __launch_bounds__(256, 4)
void stats_kernel(const float* __restrict__ x0,
                  const float* __restrict__ xcur,
                  float2* __restrict__ MS)
{
    const int tid  = threadIdx.x;
    const int w    = tid >> 6;
    const int l    = tid & 63;
    const int quad = l >> 4;
    const int col  = l & 15;
    const int t    = FINAL ? blockIdx.y : blockIdx.y + 1;
    const int b    = blockIdx.z;
    const int mb   = (blockIdx.x * 4 + w) * 16;
    const float inv_f = 0.17677669529663687f;
    const float* xs = (FINAL && t == 0) ? x0 : xcur;

    f16x8 bm = load_frag8(&xs[xidx(b, mb + col, t, quad * 8)]);

    // prefetch ring, depth 4 (raw float4 pairs)
    float4 xr[4][2];
    #pragma unroll
    for (int p = 0; p < 4; ++p) {
        const float* ap = &xs[xidx(b, p * 16 + col, t, quad * 8)];
        xr[p][0] = *reinterpret_cast<const float4*>(ap);
        xr[p][1] = *reinterpret_cast<const float4*>(ap + 4);
    }

    float M[4] = {-1e30f, -1e30f, -1e30f, -1e30f};
    float S[4] = {0.f, 0.f, 0.f, 0.f};
    #pragma unroll
    for (int nt2 = 0; nt2 < 32; ++nt2) {
        const int rb = nt2 & 3;
        f16x8 an = cvt_frag8(xr[rb][0], xr[rb][1]);
        if (nt2 + 4 < 32) {
            const float* ap = &xs[xidx(b, (nt2 + 4) * 16 + col, t, quad * 8)];
            xr[rb][0] = *reinterpret_cast<const float4*>(ap);
            xr[rb][1] = *reinterpret_cast<const float4*>(ap + 4);
        }
        f32x4 s4 = __builtin_amdgcn_mfma_f32_16x16x32_f16(
                       an, bm, (f32x4){0.f, 0.f, 0.f, 0.f}, 0, 0, 0);
        const int ss = rb;
        float m4 = fmaxf(fmaxf(s4[0], s4[1]), fmaxf(s4[2], s4[3])) * inv_f;
        float Mn = fmaxf(M[ss], m4);
        S[ss] = S[ss] * __expf(M[ss] - Mn)
              + (__expf(s4[0] * inv_f - Mn) + __expf(s4[1] * inv_f - Mn))
              + (__expf(s4[2] * inv_f - Mn) + __expf(s4[3] * inv_f - Mn));
        M[ss] = Mn;
    }
    float M01 = fmaxf(M[0], M[1]);
    float S01 = S[0] * __expf(M[0] - M01) + S[1] * __expf(M[1] - M01);
    float M23 = fmaxf(M[2], M[3]);
    float S23 = S[2] * __expf(M[2] - M23) + S[3] * __expf(M[3] - M23);
    float Mm  = fmaxf(M01, M23);
    float Sm  = S01 * __expf(M01 - Mm) + S23 * __expf(M23 - Mm);
    #pragma unroll
    for (int d = 16; d < 64; d <<= 1) {
        float Mo = __shfl_xor(Mm, d, 64), So = __shfl_xor(Sm, d, 64);
        float Mn = fmaxf(Mm, Mo);
        Sm = Sm * __expf(Mm - Mn) + So * __expf(Mo - Mn);
        Mm = Mn;
    }
    if (l < 16)
        MS[(size_t)(b * T_ + t) * N_ + mb + l] = make_float2(Mm, inv_f / Sm);
}

// ---------------------------------------------------------------------------
// Pred/agg kernel. 704 blocks x 256 thr. Wave owns n-tile bx*4+w, iterates
// 32 m-chunks with explicit pipeline: phase ring depth 8, x/bp/MS stage 1
// iteration ahead. Fully unrolled (static ring indices).
template <int FINAL>
__global__ __launch_bounds__(256, 3)
void pred_kernel(const float* __restrict__ x0,
                 const float* __restrict__ xcur,
                 float* __restrict__ dst,            // xnext or agg
                 const ushort_t* __restrict__ phase_h,
                 const ushort_t* __restrict__ adj_h,
                 const float* __restrict__ mask,
                 const float2* __restrict__ MS)
{
    const int tid  = threadIdx.x;
    const int w    = tid >> 6;
    const int l    = tid & 63;
    const int quad = l >> 4;
    const int col  = l & 15;
    const int t    = FINAL ? blockIdx.y : blockIdx.y + 1;
    const int b    = blockIdx.z;
    const int nt   = blockIdx.x * 4 + w;             // wave's n-tile
    const float inv_f = 0.17677669529663687f;

    const float* xs     = (FINAL && t == 0) ? x0 : xcur;       // X_t source
    const float* xp_src = FINAL ? xs : ((t == 1) ? x0 : xcur); // pred operand
    const int    tp     = FINAL ? t : t - 1;

    f16x8 bf = load_frag8(&xs[xidx(b, nt * 16 + col, t, quad * 8)]);
    // phase/adj as uint2 per chunk: idx = (c>>1)*4096 + (c&1)
    const uint2* phu2 = (const uint2*)((const uint4*)phase_h
                        + (size_t)(b * T_ + t) * 32768 + nt * 64 + l);
    const uint2* adu2 = (const uint2*)((const uint4*)adj_h + nt * 64 + l);
    const float* msp  = (const float*)(MS + (size_t)(b * T_ + t) * N_) + quad * 8;

    f32x4 acc0 = (f32x4){0.f, 0.f, 0.f, 0.f};
    f32x4 acc1 = (f32x4){0.f, 0.f, 0.f, 0.f};

    // ---- rings ----
    uint2  ph[8], aj[8];
    float4 xr[2][2];      // [stage][lo/hi]
    float4 msr[2][2];     // [stage][rows +0,+1 | +2,+3]
    float  bpr[2][8];     // [stage][jj:0-3 col | 4-7 col+16]

#define PH_LD(c)  phu2[(size_t)((c) >> 1) * 4096 + ((c) & 1)]
#define AD_LD(c)  adu2[(size_t)((c) >> 1) * 4096 + ((c) & 1)]
#define STAGE(s, c)                                                          \
    {                                                                        \
        const float* ap_ = &xs[xidx(b, (c) * 16 + col, t, quad * 8)];        \
        xr[s][0] = *reinterpret_cast<const float4*>(ap_);                    \
        xr[s][1] = *reinterpret_cast<const float4*>(ap_ + 4);                \
        msr[s][0] = *reinterpret_cast<const float4*>(msp + (c) * 32);        \
        msr[s][1] = *reinterpret_cast<const float4*>(msp + (c) * 32 + 4);    \
        _Pragma("unroll")                                                    \
        for (int jj = 0; jj < 4; ++jj) {                                     \
            const int r_ = (c) * 16 + quad * 4 + jj;                         \
            bpr[s][jj]     = xp_src[xidx(b, r_, tp, col)];                   \
            bpr[s][4 + jj] = xp_src[xidx(b, r_, tp, 16 + col)];              \
        }                                                                    \
    }

    #pragma unroll
    for (int p = 0; p < 8; ++p) {
        ph[p] = PH_LD(p);
        if (FINAL) aj[p] = AD_LD(p);
    }
    STAGE(0, 0);

    #pragma unroll
    for (int c = 0; c < 32; ++c) {
        const int cur = c & 1, nxt = cur ^ 1, rb = c & 7;
        if (c < 31) STAGE(nxt, c + 1);
        uint2 phq = ph[rb];
        if (c + 8 < 32) ph[rb] = PH_LD(c + 8);
        uint2 ajq;
        if (FINAL) {
            ajq = aj[rb];
            if (c + 8 < 32) aj[rb] = AD_LD(c + 8);
        }

        f16x8 af = cvt_frag8(xr[cur][0], xr[cur][1]);
        f32x4 s4 = __builtin_amdgcn_mfma_f32_16x16x32_f16(
                       af, bf, (f32x4){0.f, 0.f, 0.f, 0.f}, 0, 0, 0);

        const float Mv[4] = {msr[cur][0].x, msr[cur][0].z, msr[cur][1].x, msr[cur][1].z};
        const float Sv[4] = {msr[cur][0].y, msr[cur][0].w, msr[cur][1].y, msr[cur][1].w};
        U2H4 p0; p0.u = phq;
        U2H4 a0; if (FINAL) a0.u = ajq;
        f16x4 wf;
        #pragma unroll
        for (int v = 0; v < 4; ++v) {
            float e = __expf(s4[v] * inv_f - Mv[v]) * Sv[v] * (float)p0.h[v];
            if (FINAL) e *= (float)a0.h[v];
            wf[v] = (f16_t)e;
        }
        f16x4 bp0, bp1;
        #pragma unroll
        for (int jj = 0; jj < 4; ++jj) {
            bp0[jj] = (f16_t)bpr[cur][jj];
            bp1[jj] = (f16_t)bpr[cur][4 + jj];
        }
        acc0 = __builtin_amdgcn_mfma_f32_16x16x16f16(wf, bp0, acc0, 0, 0, 0);
        acc1 = __builtin_amdgcn_mfma_f32_16x16x16f16(wf, bp1, acc1, 0, 0, 0);
    }
#undef PH_LD
#undef AD_LD
#undef STAGE

    // ---- epilogue: exactly-once plain stores ----
    #pragma unroll
    for (int v = 0; v < 4; ++v) {
        const int n = nt * 16 + quad * 4 + v;
        if (FINAL) {
            float* d0 = &dst[((size_t)(b * T_ + t) * N_ + n) * F_ + col];
            d0[0]  = acc0[v];
            d0[16] = acc1[v];
        } else {
            const int i0 = xidx(b, n, t, col);
            const float mk = mask[n];
            dst[i0]      = (mk != 0.f) ? xcur[i0]      : acc0[v];
            dst[i0 + 16] = (mk != 0.f) ? xcur[i0 + 16] : acc1[v];
        }
    }
}

// out[b,n,t,o] = relu(sum_f agg[b,t,n,f] * theta[f,o])
__global__ __launch_bounds__(256)
void proj_kernel(const float* __restrict__ agg, const float* __restrict__ theta,
                 float* __restrict__ out)
{
    __shared__ float th[F_ * O_];
    int tid = threadIdx.x;
    #pragma unroll
    for (int p = 0; p < 8; ++p) th[tid + 256 * p] = theta[tid + 256 * p];
    __syncthreads();
    int g  = blockIdx.x * 256 + tid;           // ((b*N+n)*T+t)*O+o
    int o  = g & 63;
    int r  = g >> 6;
    int tt = r % T_;
    int r2 = r / T_;
    int n  = r2 & 511;
    int b  = r2 >> 9;
    const float* a = &agg[((b * T_ + tt) * N_ + n) * F_];
    float s = 0.f;
    #pragma unroll
    for (int f = 0; f < F_; ++f) s += a[f] * th[f * O_ + o];
    out[g] = fmaxf(s, 0.f);
}

extern "C" void kernel_launch(void* const* d_in, const int* in_sizes, int n_in,
                              void* d_out, int out_size, void* d_ws, size_t ws_size,
                              hipStream_t stream)
{
    const float* x     = (const float*)d_in[0];
    const float* phase = (const float*)d_in[1];
    const float* adj   = (const float*)d_in[2];
    const float* mask  = (const float*)d_in[3];
    const float* theta = (const float*)d_in[4];
    float* out = (float*)d_out;

    const size_t XE = (size_t)B_ * N_ * T_ * F_;            // 1,572,864 floats
    float*    xA      = (float*)d_ws;                       //  6.3 MB
    float*    xB      = xA + XE;                            //  6.3 MB
    float*    agg     = xB + XE;                            //  6.3 MB
    ushort_t* phase_h = (ushort_t*)(agg + XE);              // 50.3 MB
    ushort_t* adj_h   = phase_h + (size_t)96 * N_ * N_;     // 0.5 MB
    float2*   MS      = (float2*)(adj_h + (size_t)N_ * N_); // 0.4 MB

    permute_kernel<<<dim3(16, 96), 256, 0, stream>>>(phase, phase_h);
    permute_kernel<<<dim3(16, 1), 256, 0, stream>>>(adj, adj_h);

    const float* cur = x;
    float* bufs[2] = { xA, xB };
    for (int i = 0; i < T_ - 1; ++i) {                 // 11 Jacobi iterations
        float* nxt = bufs[i & 1];
        stats_kernel<0><<<dim3(8, T_ - 1, B_), 256, 0, stream>>>(x, cur, MS);
        pred_kernel<0><<<dim3(8, T_ - 1, B_), 256, 0, stream>>>(
            x, cur, nxt, phase_h, adj_h, mask, MS);
        cur = nxt;
    }
    stats_kernel<1><<<dim3(8, T_, B_), 256, 0, stream>>>(x, cur, MS);
    pred_kernel<1><<<dim3(8, T_, B_), 256, 0, stream>>>(
        x, cur, agg, phase_h, adj_h, mask, MS);
    proj_kernel<<<(B_ * N_ * T_ * O_) / 256, 256, 0, stream>>>(agg, theta, out);
}